// Round 6
// baseline (138.796 us; speedup 1.0000x reference)
//
#include <hip/hip_runtime.h>
#include <hip/hip_bf16.h>
#include <stdint.h>

#define N      2048
#define NFEAT  512
#define NHID   64
#define NCLASS 64
#define NHEADS 8
#define ALPHA  0.2f
#define NW     (N / 64)   // 32 bitmask words per row

typedef __attribute__((ext_vector_type(8))) short bf16x8;
typedef __attribute__((ext_vector_type(4))) float f32x4;

__device__ __forceinline__ short f2bf(float f) {
    union { float f; unsigned u; } v; v.f = f;
    unsigned r = v.u + 0x7fffu + ((v.u >> 16) & 1u);   // RNE
    return (short)(r >> 16);
}
__device__ __forceinline__ float bf2f(short s) {
    union { unsigned u; float f; } v; v.u = ((unsigned)(unsigned short)s) << 16;
    return v.f;
}
__device__ __forceinline__ unsigned pack2(float a, float b) {
    return (unsigned)(unsigned short)f2bf(a) | ((unsigned)(unsigned short)f2bf(b) << 16);
}

// ================================================================ prep (the ONE change vs round 2):
// blocks [0,256)   : pack adj -> bitmask (8 rows per block)
// blocks [256,512) : x f32 -> bf16 row-major
// blocks [512,576) : W  [8][512][64] f32 -> Wtb  [8][64][512] bf16
// blocks [576,584) : Wf [512][64]   f32 -> Wftb [64][512]    bf16
__global__ __launch_bounds__(256) void prep_kernel(
        const int* __restrict__ adj, const float* __restrict__ x,
        const float* __restrict__ W, const float* __restrict__ Wf,
        unsigned long long* __restrict__ bits, short* __restrict__ xb,
        short* __restrict__ Wtb, short* __restrict__ Wftb) {
    __shared__ float tile[64][65];
    const int b = blockIdx.x;
    const int t = threadIdx.x;
    if (b < 256) {
        int wave = t >> 6, lane = t & 63;
        #pragma unroll
        for (int rr = 0; rr < 8; ++rr) {
            int i = b * 8 + rr;
            for (int w = wave; w < NW; w += 4) {
                unsigned long long m = __ballot(adj[(size_t)i * N + w * 64 + lane] > 0);
                if (lane == 0) bits[(size_t)i * NW + w] = m;
            }
        }
    } else if (b < 512) {
        int base = (b - 256) * 512 + t;
        #pragma unroll
        for (int q = 0; q < 2; ++q) {
            int idx = base + q * 256;                      // uint4 index (8 floats)
            const float4 a = ((const float4*)x)[idx * 2];
            const float4 c = ((const float4*)x)[idx * 2 + 1];
            ((uint4*)xb)[idx] = make_uint4(pack2(a.x, a.y), pack2(a.z, a.w),
                                           pack2(c.x, c.y), pack2(c.z, c.w));
        }
    } else {
        const float* src_base; short* dst_base; int r0;
        if (b < 576) {
            int idx = b - 512;
            int h = idx >> 3; r0 = (idx & 7) * 64;
            src_base = W + (size_t)h * 512 * 64;
            dst_base = Wtb + (size_t)h * 64 * 512;
        } else {
            int idx = b - 576; r0 = idx * 64;
            src_base = Wf; dst_base = Wftb;
        }
        {
            int r = t >> 2, cq = (t & 3) * 16;
            const float* src = src_base + (size_t)(r0 + r) * 64 + cq;
            #pragma unroll
            for (int q = 0; q < 4; ++q) {
                float4 v = ((const float4*)src)[q];
                tile[r][cq + q * 4 + 0] = v.x; tile[r][cq + q * 4 + 1] = v.y;
                tile[r][cq + q * 4 + 2] = v.z; tile[r][cq + q * 4 + 3] = v.w;
            }
        }
        __syncthreads();
        {
            int c = t >> 2, rq = (t & 3) * 16;
            unsigned u[8];
            #pragma unroll
            for (int p = 0; p < 8; ++p)
                u[p] = pack2(tile[rq + 2 * p][c], tile[rq + 2 * p + 1][c]);
            short* dst = dst_base + (size_t)c * 512 + r0 + rq;
            ((uint4*)dst)[0] = make_uint4(u[0], u[1], u[2], u[3]);
            ((uint4*)dst)[1] = make_uint4(u[4], u[5], u[6], u[7]);
        }
    }
}

// ================================================================ bf16 MFMA GEMM (round-2 verbatim)
template <int RT>
__global__ __launch_bounds__(256) void gemm_mfma(const short* __restrict__ Ab,
                                                 const short* __restrict__ Btb,
                                                 short* __restrict__ Ctb,
                                                 int M, int K) {
    const int h = blockIdx.y;
    const int t = threadIdx.x, wave = t >> 6, lane = t & 63;
    const int c = lane & 15, g = lane >> 4;
    const int i0 = blockIdx.x * (4 * RT * 16) + wave * (RT * 16);
    const short* Bh = Btb + (size_t)h * 64 * K;
    f32x4 acc[RT][4];
    #pragma unroll
    for (int rt = 0; rt < RT; ++rt)
        #pragma unroll
        for (int dt = 0; dt < 4; ++dt) { acc[rt][dt][0]=0.f; acc[rt][dt][1]=0.f; acc[rt][dt][2]=0.f; acc[rt][dt][3]=0.f; }
    for (int k0 = 0; k0 < K; k0 += 32) {
        bf16x8 af[RT];
        #pragma unroll
        for (int rt = 0; rt < RT; ++rt)
            af[rt] = *(const bf16x8*)(Ab + (size_t)(i0 + rt * 16 + c) * K + k0 + g * 8);
        #pragma unroll
        for (int dt = 0; dt < 4; ++dt) {
            bf16x8 bf = *(const bf16x8*)(Bh + (size_t)(dt * 16 + c) * K + k0 + g * 8);
            #pragma unroll
            for (int rt = 0; rt < RT; ++rt)
                acc[rt][dt] = __builtin_amdgcn_mfma_f32_16x16x32_bf16(af[rt], bf, acc[rt][dt], 0, 0, 0);
        }
    }
    #pragma unroll
    for (int rt = 0; rt < RT; ++rt)
        #pragma unroll
        for (int dt = 0; dt < 4; ++dt) {
            int n = dt * 16 + c;
            int i = i0 + rt * 16 + g * 4;
            uint2 u = make_uint2(pack2(acc[rt][dt][0], acc[rt][dt][1]),
                                 pack2(acc[rt][dt][2], acc[rt][dt][3]));
            *(uint2*)(Ctb + (size_t)(h * 64 + n) * M + i) = u;
        }
}

// ================================================================ s1,s2 (round-2 verbatim)
__global__ void scores_t(const short* __restrict__ Htb, const float* __restrict__ a1,
                         const float* __restrict__ a2, float* __restrict__ s1,
                         float* __restrict__ s2) {
    int h = blockIdx.y;
    int i = blockIdx.x * 256 + threadIdx.x;
    float p1 = 0.f, p2 = 0.f;
    #pragma unroll 8
    for (int d = 0; d < 64; ++d) {
        float hv = bf2f(Htb[(size_t)(h * 64 + d) * N + i]);
        p1 += hv * a1[h * 64 + d];
        p2 += hv * a2[h * 64 + d];
    }
    s1[h * N + i] = p1;
    s2[h * N + i] = p2;
}

// ================================================================ per-row masked max (round-2 verbatim)
__global__ void rowmax_k(const unsigned long long* __restrict__ bits,
                         const float* __restrict__ s1h, const float* __restrict__ s2h,
                         float* __restrict__ emaxh) {
    int gid  = blockIdx.x * 4 + (threadIdx.x >> 6);
    int lane = threadIdx.x & 63;
    int h = gid >> 11;            // / N
    int i = gid & (N - 1);
    const float* s1 = s1h + (size_t)h * N;
    unsigned long long word = bits[(size_t)i * NW + (lane >> 1)];
    unsigned hw = (lane & 1) ? (unsigned)(word >> 32) : (unsigned)word;
    int j0 = lane * 32;
    float mx = -3e38f;
    #pragma unroll
    for (int q = 0; q < 8; ++q) {
        float4 v = *(const float4*)(s1 + j0 + q * 4);
        if ((hw >> (q * 4 + 0)) & 1) mx = fmaxf(mx, v.x);
        if ((hw >> (q * 4 + 1)) & 1) mx = fmaxf(mx, v.y);
        if ((hw >> (q * 4 + 2)) & 1) mx = fmaxf(mx, v.z);
        if ((hw >> (q * 4 + 3)) & 1) mx = fmaxf(mx, v.w);
    }
    #pragma unroll
    for (int off = 32; off; off >>= 1) mx = fmaxf(mx, __shfl_xor(mx, off));
    if (lane == 0) {
        float e = mx + s2h[(size_t)h * N + i];
        emaxh[(size_t)h * N + i] = fmaxf(e, ALPHA * e);
    }
}

// ================================================================ fused masked-softmax + PV (round-2 verbatim)
// MODE 0: outB bf16 [i][h*64+d] = elu(att@H); MODE 1: outF f32 partials + psum (z-split).
template <int RT, int MODE>
__global__ __launch_bounds__(256) void attn_mfma(
        const unsigned long long* __restrict__ bits,
        const float* __restrict__ s1h, const float* __restrict__ s2h,
        const float* __restrict__ emaxh,
        const short* __restrict__ Htb,
        short* __restrict__ outB, float* __restrict__ outF, float* __restrict__ psum,
        int jwords_per_z) {
    const int h = blockIdx.y;
    const int z = blockIdx.z;
    const int i0 = blockIdx.x * (RT * 16);
    const int t = threadIdx.x;
    const int wave = t >> 6, lane = t & 63;
    const int c = lane & 15, g = lane >> 4;

    const float* s1 = s1h + (size_t)h * N;
    const unsigned long long* brow[RT];
    float s2v[RT], emv[RT];
    #pragma unroll
    for (int rt = 0; rt < RT; ++rt) {
        int i = i0 + rt * 16 + c;
        brow[rt] = bits + (size_t)i * NW;
        s2v[rt] = s2h[(size_t)h * N + i];
        emv[rt] = emaxh[(size_t)h * N + i];
    }

    f32x4 acc[RT][4];
    #pragma unroll
    for (int rt = 0; rt < RT; ++rt)
        #pragma unroll
        for (int dt = 0; dt < 4; ++dt) { acc[rt][dt][0]=0.f; acc[rt][dt][1]=0.f; acc[rt][dt][2]=0.f; acc[rt][dt][3]=0.f; }
    float wsum[RT];
    #pragma unroll
    for (int rt = 0; rt < RT; ++rt) wsum[rt] = 0.f;

    const int nchunk = jwords_per_z * 2;
    const int cbase  = z * nchunk;
    for (int cc = wave; cc < nchunk; cc += 4) {
        const int j0 = (cbase + cc) * 32;
        const int wi = j0 >> 6;
        const int sh = (j0 & 32) + g * 8;
        const float4 q0 = *(const float4*)(s1 + j0 + g * 8);
        const float4 q1 = *(const float4*)(s1 + j0 + g * 8 + 4);
        const float s1e[8] = {q0.x, q0.y, q0.z, q0.w, q1.x, q1.y, q1.z, q1.w};
        bf16x8 af[RT];
        #pragma unroll
        for (int rt = 0; rt < RT; ++rt) {
            unsigned byte = (unsigned)(brow[rt][wi] >> sh) & 0xffu;
            #pragma unroll
            for (int e = 0; e < 8; ++e) {
                float ev = s1e[e] + s2v[rt];
                ev = fmaxf(ev, ALPHA * ev);                       // LeakyReLU
                float w = ((byte >> e) & 1u) ? __expf(ev - emv[rt]) : 0.f;
                wsum[rt] += w;
                af[rt][e] = f2bf(w);
            }
        }
        #pragma unroll
        for (int dt = 0; dt < 4; ++dt) {
            bf16x8 bf = *(const bf16x8*)(Htb + (size_t)(h * 64 + dt * 16 + c) * N + j0 + g * 8);
            #pragma unroll
            for (int rt = 0; rt < RT; ++rt)
                acc[rt][dt] = __builtin_amdgcn_mfma_f32_16x16x32_bf16(af[rt], bf, acc[rt][dt], 0, 0, 0);
        }
    }

    #pragma unroll
    for (int rt = 0; rt < RT; ++rt) {
        wsum[rt] += __shfl_xor(wsum[rt], 16);
        wsum[rt] += __shfl_xor(wsum[rt], 32);
    }

    __shared__ float redC[4][RT * 16][66];
    __shared__ float redS[4][RT * 16];
    __shared__ float wsumL[RT * 16];
    #pragma unroll
    for (int rt = 0; rt < RT; ++rt) {
        if (g == 0) redS[wave][rt * 16 + c] = wsum[rt];
        #pragma unroll
        for (int dt = 0; dt < 4; ++dt)
            #pragma unroll
            for (int r = 0; r < 4; ++r)
                redC[wave][rt * 16 + g * 4 + r][dt * 16 + c] = acc[rt][dt][r];
    }
    __syncthreads();
    if (t < RT * 16) wsumL[t] = redS[0][t] + redS[1][t] + redS[2][t] + redS[3][t];
    __syncthreads();

    for (int idx = t; idx < RT * 16 * 64; idx += 256) {
        int r = idx >> 6, d = idx & 63;
        float v = redC[0][r][d] + redC[1][r][d] + redC[2][r][d] + redC[3][r][d];
        if (MODE == 0) {
            v /= wsumL[r];
            v = v > 0.f ? v : (__expf(v) - 1.f);                  // fused elu
            outB[(size_t)(i0 + r) * (NHEADS * NHID) + h * 64 + d] = f2bf(v);
        } else {
            outF[((size_t)z * N + i0 + r) * 64 + d] = v;          // unnormalized partial
        }
    }
    if (MODE == 1 && t < RT * 16) psum[(size_t)z * N + i0 + t] = wsumL[t];
}

// ================================================================ combine 2 j-partials (round-2 verbatim)
__global__ void combine2(const float* __restrict__ pout, const float* __restrict__ psum,
                         float* __restrict__ outp) {
    int idx = blockIdx.x * 256 + threadIdx.x;   // N*64
    int i = idx >> 6;
    float a = pout[idx] + pout[(size_t)N * 64 + idx];
    float s = psum[i] + psum[N + i];
    outp[idx] = a / s;
}

// ================================================================ launch (10 dispatches; round-2 + fused prep ONLY)
extern "C" void kernel_launch(void* const* d_in, const int* in_sizes, int n_in,
                              void* d_out, int out_size, void* d_ws, size_t ws_size,
                              hipStream_t stream) {
    const float* x   = (const float*)d_in[0];
    const int*   adj = (const int*)d_in[1];
    const float* W   = (const float*)d_in[2];
    const float* a1  = (const float*)d_in[3];
    const float* a2  = (const float*)d_in[4];
    const float* Wf  = (const float*)d_in[5];
    const float* a1f = (const float*)d_in[6];
    const float* a2f = (const float*)d_in[7];
    float* out = (float*)d_out;

    char* ws = (char*)d_ws;
    unsigned long long* bits = (unsigned long long*)ws; ws += (size_t)N * NW * 8;  // 512 KB
    short* xb   = (short*)ws; ws += (size_t)N * 512 * 2;        // 2 MB
    short* Wtb  = (short*)ws; ws += (size_t)8 * 64 * 512 * 2;   // 512 KB
    short* Wftb = (short*)ws; ws += (size_t)64 * 512 * 2;       // 64 KB
    short* Htb  = (short*)ws; ws += (size_t)512 * N * 2;        // 2 MB  [h*64+d][j]
    short* x2b  = (short*)ws; ws += (size_t)N * 512 * 2;        // 2 MB  [i][h*64+d]
    short* H2tb = (short*)ws; ws += (size_t)64 * N * 2;         // 256 KB
    float* s1   = (float*)ws; ws += (size_t)NHEADS * N * 4;
    float* s2   = (float*)ws; ws += (size_t)NHEADS * N * 4;
    float* emax = (float*)ws; ws += (size_t)NHEADS * N * 4;
    float* s1f  = (float*)ws; ws += (size_t)N * 4;
    float* s2f  = (float*)ws; ws += (size_t)N * 4;
    float* emaxf= (float*)ws; ws += (size_t)N * 4;
    float* pout = (float*)ws; ws += (size_t)2 * N * 64 * 4;     // 1 MB
    float* psum = (float*)ws; ws += (size_t)2 * N * 4;

    // 1) prep: pack adj + cvt x + transpose-cvt W, Wf   (the only change vs round 2)
    prep_kernel<<<584, 256, 0, stream>>>(adj, x, W, Wf, bits, xb, Wtb, Wftb);
    // 2) layer-1 projection
    gemm_mfma<2><<<dim3(16, 8), 256, 0, stream>>>(xb, Wtb, Htb, N, 512);
    // 3) layer-1 scores
    scores_t<<<dim3(N / 256, 8), 256, 0, stream>>>(Htb, a1, a2, s1, s2);
    // 4) layer-1 row max
    rowmax_k<<<(N * 8) / 4, 256, 0, stream>>>(bits, s1, s2, emax);
    // 5) layer-1 fused masked softmax + PV + elu
    attn_mfma<2, 0><<<dim3(N / 32, 8, 1), 256, 0, stream>>>(bits, s1, s2, emax, Htb,
                                                            x2b, nullptr, nullptr, NW);
    // 6) layer-2 projection
    gemm_mfma<2><<<dim3(16, 1), 256, 0, stream>>>(x2b, Wftb, H2tb, N, 512);
    // 7) layer-2 scores
    scores_t<<<dim3(N / 256, 1), 256, 0, stream>>>(H2tb, a1f, a2f, s1f, s2f);
    // 8) layer-2 row max
    rowmax_k<<<(N * 1) / 4, 256, 0, stream>>>(bits, s1f, s2f, emaxf);
    // 9) layer-2 attention, z-split 2, unnormalized partials
    attn_mfma<1, 1><<<dim3(N / 16, 1, 2), 256, 0, stream>>>(bits, s1f, s2f, emaxf, H2tb,
                                                            nullptr, pout, psum, NW / 2);
    // 10) combine partials -> d_out
    combine2<<<(N * 64) / 256, 256, 0, stream>>>(pout, psum, out);
}